// Round 3
// baseline (532.245 us; speedup 1.0000x reference)
//
#include <hip/hip_runtime.h>
#include <hip/hip_bf16.h>

// Causal MHA forward — bf16 MFMA everywhere, fp32 softmax/accumulate.
//   x      [4, 2048, 1024]   d_in[0] fp32
//   w_qkv  [3, 16, 64, 1024] d_in[1] fp32 ([3072,1024], K contiguous)
//   w_o    [1024, 1024]      d_in[2] fp32 (y = attn_cat @ w_o^T)
//   out    [4, 2048, 1024]   d_out   fp32
// ws: qkv [3][4][16][2048][64] f32 (100 MB) + attn_cat [8192][1024] f32 (32 MB).

#define D_MODEL 1024
#define NUM_HEADS 16
#define D_KD 64
#define B_SZ 4
#define S_LEN 2048
#define ROWS (B_SZ * S_LEN)   // 8192
#define QKV_N (3 * D_MODEL)   // 3072

typedef __attribute__((ext_vector_type(8))) short short8;
typedef __attribute__((ext_vector_type(4))) float f32x4;

__device__ __forceinline__ unsigned f2bf(float f) {
    unsigned u = __builtin_bit_cast(unsigned, f);
    return (u + 0x7FFFu + ((u >> 16) & 1u)) >> 16;   // RNE, finite inputs
}
__device__ __forceinline__ uint2 pack_bf16x4(float4 v) {
    uint2 u;
    u.x = f2bf(v.x) | (f2bf(v.y) << 16);
    u.y = f2bf(v.z) | (f2bf(v.w) << 16);
    return u;
}
__device__ __forceinline__ short8 pack_bf16x8(const float* p) {
    union { unsigned u[4]; short8 s; } r;
#pragma unroll
    for (int i = 0; i < 4; ++i) r.u[i] = f2bf(p[2 * i]) | (f2bf(p[2 * i + 1]) << 16);
    return r.s;
}

// ---------------------------------------------------------------------------
// MFMA GEMM: C = A * B^T. A:[M,K] f32 row-major, B:[N,K] f32 row-major.
// 128x128 tile, BK=32, 4 waves 2x2, 4x4 16x16x32 fragments per wave.
// MODE 0: scatter C into qkv[q][b][h][s][k]. MODE 1: row-major C.
// ---------------------------------------------------------------------------
template <int MODE>
__global__ __launch_bounds__(256) void gemm_bt_mfma(const float* __restrict__ A,
                                                    const float* __restrict__ Bm,
                                                    float* __restrict__ C,
                                                    int M, int N, int K) {
    __shared__ unsigned short As[128][40];   // 80 B rows: 2-way on reads/writes
    __shared__ unsigned short Bs[128][40];

    const int t = threadIdx.x;
    const int lane = t & 63;
    const int w = t >> 6;
    const int wr = w >> 1, wc = w & 1;
    const int row0 = blockIdx.y * 128;
    const int col0 = blockIdx.x * 128;

    const int srow = t >> 3;           // 0..31 (+i*32)
    const int skc = (t & 7) << 2;      // f32 k offset 0..28

    const float* Abase = A + (size_t)row0 * K;
    const float* Bbase = Bm + (size_t)col0 * K;

    f32x4 acc[4][4];
#pragma unroll
    for (int m = 0; m < 4; ++m)
#pragma unroll
        for (int n = 0; n < 4; ++n)
#pragma unroll
            for (int j = 0; j < 4; ++j) acc[m][n][j] = 0.f;

    float4 pa[4], pb[4];
    const int q8 = (lane >> 4) << 3;           // bf16 k offset in BK=32
    const int frA = wr * 64 + (lane & 15);
    const int frB = wc * 64 + (lane & 15);
    const int NT = K >> 5;

#pragma unroll
    for (int i = 0; i < 4; ++i) {
        int r = i * 32 + srow;
        pa[i] = *reinterpret_cast<const float4*>(&Abase[(size_t)r * K + skc]);
        pb[i] = *reinterpret_cast<const float4*>(&Bbase[(size_t)r * K + skc]);
    }

    for (int kt = 0; kt < NT; ++kt) {
        __syncthreads();
#pragma unroll
        for (int i = 0; i < 4; ++i) {
            int r = i * 32 + srow;
            *reinterpret_cast<uint2*>(&As[r][skc]) = pack_bf16x4(pa[i]);
            *reinterpret_cast<uint2*>(&Bs[r][skc]) = pack_bf16x4(pb[i]);
        }
        __syncthreads();

        if (kt + 1 < NT) {
            const int k0n = (kt + 1) << 5;
#pragma unroll
            for (int i = 0; i < 4; ++i) {
                int r = i * 32 + srow;
                pa[i] = *reinterpret_cast<const float4*>(&Abase[(size_t)r * K + k0n + skc]);
                pb[i] = *reinterpret_cast<const float4*>(&Bbase[(size_t)r * K + k0n + skc]);
            }
        }

        short8 afr[4], bfr[4];
#pragma unroll
        for (int m = 0; m < 4; ++m)
            afr[m] = *reinterpret_cast<const short8*>(&As[frA + m * 16][q8]);
#pragma unroll
        for (int n = 0; n < 4; ++n)
            bfr[n] = *reinterpret_cast<const short8*>(&Bs[frB + n * 16][q8]);
#pragma unroll
        for (int m = 0; m < 4; ++m)
#pragma unroll
            for (int n = 0; n < 4; ++n)
                acc[m][n] = __builtin_amdgcn_mfma_f32_16x16x32_bf16(afr[m], bfr[n],
                                                                    acc[m][n], 0, 0, 0);
    }

    // C/D frag: col = lane&15, row = (lane>>4)*4 + reg.
    const int orow = row0 + wr * 64 + ((lane >> 4) << 2);
    const int ocol = col0 + wc * 64 + (lane & 15);
#pragma unroll
    for (int m = 0; m < 4; ++m)
#pragma unroll
        for (int n = 0; n < 4; ++n) {
            const int cg = ocol + n * 16;
#pragma unroll
            for (int j = 0; j < 4; ++j) {
                const int rg = orow + m * 16 + j;
                const float v = acc[m][n][j];
                if (MODE == 0) {
                    int q = cg >> 10, h = (cg >> 6) & 15, kk = cg & 63;
                    int b = rg >> 11, s = rg & 2047;
                    C[((((size_t)q * B_SZ + b) * NUM_HEADS + h) * S_LEN + s) * D_KD + kk] = v;
                } else {
                    C[(size_t)rg * N + cg] = v;
                }
            }
        }
}

// ---------------------------------------------------------------------------
// Flash attention, bf16 MFMA QK^T + PV, fp32 online softmax.
// One block per (b, h, 64-row q tile); 4 waves in 2x2, each owns 32x32 of
// the 64x64 S / O tiles (2x2 fragments of mfma_f32_16x16x32_bf16).
// Q staged once (scaled 1/8); per kv-tile: K rows bf16, V transposed bf16
// (per-thread 4x4 register transpose -> 4 ds_write_b64).
// ---------------------------------------------------------------------------
__global__ __launch_bounds__(256) void flash_attn_mfma(const float* __restrict__ qkv,
                                                       float* __restrict__ attn_out) {
    const int qt = blockIdx.x;
    const int h = blockIdx.y;
    const int b = blockIdx.z;
    const int t = threadIdx.x;
    const int lane = t & 63;
    const int w = t >> 6;
    const int wr = w >> 1, wc = w & 1;

    __shared__ unsigned short Qs[64][72];   // [q][k] bf16, pre-scaled 1/8
    __shared__ unsigned short Ks[64][72];   // [t][k] bf16
    __shared__ unsigned short Vt[64][72];   // [dk][t] bf16 (V transposed)
    __shared__ float Ss[64][68];            // scores -> probs (fp32)
    __shared__ float sm_m[64], sm_l[64], sm_al[64];
    __shared__ float redm[64][4], redl[64][4];

    const size_t head_elems = (size_t)S_LEN * D_KD;
    const float* Qg = qkv + (((size_t)0 * B_SZ + b) * NUM_HEADS + h) * head_elems;
    const float* Kg = qkv + (((size_t)1 * B_SZ + b) * NUM_HEADS + h) * head_elems;
    const float* Vg = qkv + (((size_t)2 * B_SZ + b) * NUM_HEADS + h) * head_elems;

    const int q0 = qt * 64;

    // Stage Q once (x 0.125 folded in; exact scaling)
#pragma unroll
    for (int l = 0; l < 4; ++l) {
        int idx = t + l * 256;
        int r = idx >> 4;
        int c = (idx & 15) << 2;
        float4 v = *reinterpret_cast<const float4*>(&Qg[(size_t)(q0 + r) * D_KD + c]);
        v.x *= 0.125f; v.y *= 0.125f; v.z *= 0.125f; v.w *= 0.125f;
        *reinterpret_cast<uint2*>(&Qs[r][c]) = pack_bf16x4(v);
    }
    if (t < 64) {
        sm_m[t] = -1e30f;
        sm_l[t] = 0.f;
    }

    f32x4 acc[2][2];
#pragma unroll
    for (int m = 0; m < 2; ++m)
#pragma unroll
        for (int n = 0; n < 2; ++n)
#pragma unroll
            for (int j = 0; j < 4; ++j) acc[m][n][j] = 0.f;

    const int frq8 = (lane >> 4) << 3;          // k offset within 32-step
    const int arow = wr * 32 + (lane & 15);     // A rows (q)
    const int brow = wc * 32 + (lane & 15);     // B rows (t for QK^T, dk for PV)
    const int srowb = wr * 32 + ((lane >> 4) << 2);  // C/D row base
    const int scolb = wc * 32 + (lane & 15);         // C/D col base

    const int ntiles = qt + 1;
    for (int tt = 0; tt < ntiles; ++tt) {
        const int c0 = tt * 64;
        __syncthreads();   // previous iteration done reading Ks/Vt/Ss

        // Stage K tile rows (bf16)
#pragma unroll
        for (int l = 0; l < 4; ++l) {
            int idx = t + l * 256;
            int r = idx >> 4;
            int c = (idx & 15) << 2;
            float4 v = *reinterpret_cast<const float4*>(&Kg[(size_t)(c0 + r) * D_KD + c]);
            *reinterpret_cast<uint2*>(&Ks[r][c]) = pack_bf16x4(v);
        }
        // Stage V transposed: thread owns 4x4 block (t0..t0+3) x (dk0..dk0+3)
        {
            const int t0 = (t >> 4) << 2;
            const int dk0 = (t & 15) << 2;
            float4 vv[4];
#pragma unroll
            for (int i = 0; i < 4; ++i)
                vv[i] = *reinterpret_cast<const float4*>(&Vg[(size_t)(c0 + t0 + i) * D_KD + dk0]);
            const float* vp = reinterpret_cast<const float*>(&vv[0]);
#pragma unroll
            for (int j = 0; j < 4; ++j) {
                uint2 u;
                u.x = f2bf(vp[0 * 4 + j]) | (f2bf(vp[1 * 4 + j]) << 16);
                u.y = f2bf(vp[2 * 4 + j]) | (f2bf(vp[3 * 4 + j]) << 16);
                *reinterpret_cast<uint2*>(&Vt[dk0 + j][t0]) = u;
            }
        }
        __syncthreads();

        // ---- QK^T (scaled): S = (Q/8) K^T, causal mask, -> Ss fp32
        {
            short8 qa[2][2], kb[2][2];
#pragma unroll
            for (int m = 0; m < 2; ++m)
#pragma unroll
                for (int ks = 0; ks < 2; ++ks)
                    qa[m][ks] = *reinterpret_cast<const short8*>(&Qs[arow + m * 16][ks * 32 + frq8]);
#pragma unroll
            for (int n = 0; n < 2; ++n)
#pragma unroll
                for (int ks = 0; ks < 2; ++ks)
                    kb[n][ks] = *reinterpret_cast<const short8*>(&Ks[brow + n * 16][ks * 32 + frq8]);

            f32x4 s[2][2];
#pragma unroll
            for (int m = 0; m < 2; ++m)
#pragma unroll
                for (int n = 0; n < 2; ++n) {
#pragma unroll
                    for (int j = 0; j < 4; ++j) s[m][n][j] = 0.f;
#pragma unroll
                    for (int ks = 0; ks < 2; ++ks)
                        s[m][n] = __builtin_amdgcn_mfma_f32_16x16x32_bf16(qa[m][ks], kb[n][ks],
                                                                          s[m][n], 0, 0, 0);
                }
#pragma unroll
            for (int m = 0; m < 2; ++m)
#pragma unroll
                for (int n = 0; n < 2; ++n) {
                    const int cl = scolb + n * 16;
#pragma unroll
                    for (int j = 0; j < 4; ++j) {
                        const int rl = srowb + m * 16 + j;
                        Ss[rl][cl] = (c0 + cl > q0 + rl) ? -1e30f : s[m][n][j];
                    }
                }
        }
        __syncthreads();

        // ---- Online softmax (fp32, 4 workers/row) — unchanged block
        {
            int r = t >> 2, g = t & 3;
            float v[16];
#pragma unroll
            for (int c4 = 0; c4 < 4; ++c4)
                *reinterpret_cast<float4*>(&v[c4 * 4]) =
                    *reinterpret_cast<float4*>(&Ss[r][g * 16 + c4 * 4]);
            float mx = -1e30f;
#pragma unroll
            for (int c = 0; c < 16; ++c) mx = fmaxf(mx, v[c]);
            redm[r][g] = mx;
            __syncthreads();
            float mnew = fmaxf(sm_m[r],
                               fmaxf(fmaxf(redm[r][0], redm[r][1]),
                                     fmaxf(redm[r][2], redm[r][3])));
            float ps = 0.f;
#pragma unroll
            for (int c = 0; c < 16; ++c) {
                v[c] = __expf(v[c] - mnew);
                ps += v[c];
            }
#pragma unroll
            for (int c4 = 0; c4 < 4; ++c4)
                *reinterpret_cast<float4*>(&Ss[r][g * 16 + c4 * 4]) =
                    *reinterpret_cast<float4*>(&v[c4 * 4]);
            redl[r][g] = ps;
            __syncthreads();
            if (g == 0) {
                float al = __expf(sm_m[r] - mnew);
                sm_al[r] = al;
                sm_l[r] = sm_l[r] * al + redl[r][0] + redl[r][1] + redl[r][2] + redl[r][3];
                sm_m[r] = mnew;
            }
            __syncthreads();
        }

        // ---- O = O*alpha + P V   (alpha folded into accumulator, PV via MFMA)
        {
#pragma unroll
            for (int m = 0; m < 2; ++m) {
#pragma unroll
                for (int j = 0; j < 4; ++j) {
                    const float al = sm_al[srowb + m * 16 + j];
#pragma unroll
                    for (int n = 0; n < 2; ++n) acc[m][n][j] *= al;
                }
            }
#pragma unroll
            for (int ks = 0; ks < 2; ++ks) {
                short8 pa[2], vb[2];
#pragma unroll
                for (int m = 0; m < 2; ++m) {
                    float p8[8];
                    *reinterpret_cast<float4*>(&p8[0]) =
                        *reinterpret_cast<float4*>(&Ss[arow + m * 16][ks * 32 + frq8]);
                    *reinterpret_cast<float4*>(&p8[4]) =
                        *reinterpret_cast<float4*>(&Ss[arow + m * 16][ks * 32 + frq8 + 4]);
                    pa[m] = pack_bf16x8(p8);
                }
#pragma unroll
                for (int n = 0; n < 2; ++n)
                    vb[n] = *reinterpret_cast<const short8*>(&Vt[brow + n * 16][ks * 32 + frq8]);
#pragma unroll
                for (int m = 0; m < 2; ++m)
#pragma unroll
                    for (int n = 0; n < 2; ++n)
                        acc[m][n] = __builtin_amdgcn_mfma_f32_16x16x32_bf16(pa[m], vb[n],
                                                                            acc[m][n], 0, 0, 0);
            }
        }
    }

    // Normalize + store to attn_cat [b, s, h*64 + dk]
#pragma unroll
    for (int m = 0; m < 2; ++m)
#pragma unroll
        for (int j = 0; j < 4; ++j) {
            const int rl = srowb + m * 16 + j;
            const float inv = 1.f / sm_l[rl];
            const size_t base = ((size_t)(b * S_LEN + q0 + rl)) * D_MODEL + h * D_KD;
#pragma unroll
            for (int n = 0; n < 2; ++n)
                attn_out[base + scolb + n * 16] = acc[m][n][j] * inv;
        }
}

// ---------------------------------------------------------------------------
extern "C" void kernel_launch(void* const* d_in, const int* in_sizes, int n_in,
                              void* d_out, int out_size, void* d_ws, size_t ws_size,
                              hipStream_t stream) {
    const float* x = (const float*)d_in[0];
    const float* w_qkv = (const float*)d_in[1];
    const float* w_o = (const float*)d_in[2];
    float* out = (float*)d_out;

    float* qkv = (float*)d_ws;
    float* attn = qkv + (size_t)3 * B_SZ * NUM_HEADS * S_LEN * D_KD;

    dim3 blk(256);
    gemm_bt_mfma<0><<<dim3(QKV_N / 128, ROWS / 128), blk, 0, stream>>>(
        x, w_qkv, qkv, ROWS, QKV_N, D_MODEL);
    flash_attn_mfma<<<dim3(S_LEN / 64, NUM_HEADS, B_SZ), blk, 0, stream>>>(qkv, attn);
    gemm_bt_mfma<1><<<dim3(D_MODEL / 128, ROWS / 128), blk, 0, stream>>>(
        attn, w_o, out, ROWS, D_MODEL, D_MODEL);
}

// Round 6
// 364.343 us; speedup vs baseline: 1.4608x; 1.4608x over previous
//
#include <hip/hip_runtime.h>
#include <hip/hip_bf16.h>

// Causal MHA forward — bf16 MFMA everywhere, fp32 softmax/accumulate.
//   x      [4, 2048, 1024]   d_in[0] fp32
//   w_qkv  [3, 16, 64, 1024] d_in[1] fp32 ([3072,1024], K contiguous)
//   w_o    [1024, 1024]      d_in[2] fp32 (y = attn_cat @ w_o^T)
//   out    [4, 2048, 1024]   d_out   fp32
// ws: qkv [3][4][16][2048][64] f32 (100 MB) + attn_cat [8192][1024] f32 (32 MB).

#define D_MODEL 1024
#define NUM_HEADS 16
#define D_KD 64
#define B_SZ 4
#define S_LEN 2048
#define ROWS (B_SZ * S_LEN)   // 8192
#define QKV_N (3 * D_MODEL)   // 3072

typedef __attribute__((ext_vector_type(8))) short short8;
typedef __attribute__((ext_vector_type(4))) float f32x4;
typedef __attribute__((ext_vector_type(16))) float f32x16;

__device__ __forceinline__ unsigned f2bf(float f) {
    unsigned u = __builtin_bit_cast(unsigned, f);
    return (u + 0x7FFFu + ((u >> 16) & 1u)) >> 16;   // RNE, finite inputs
}
__device__ __forceinline__ uint2 pack_bf16x4(float4 v) {
    uint2 u;
    u.x = f2bf(v.x) | (f2bf(v.y) << 16);
    u.y = f2bf(v.z) | (f2bf(v.w) << 16);
    return u;
}

// ---------------------------------------------------------------------------
// MFMA GEMM: C = A * B^T. A:[M,K] f32 row-major, B:[N,K] f32 row-major.
// (unchanged — verified working round 3: PASS, ~370 TF)
// ---------------------------------------------------------------------------
template <int MODE>
__global__ __launch_bounds__(256) void gemm_bt_mfma(const float* __restrict__ A,
                                                    const float* __restrict__ Bm,
                                                    float* __restrict__ C,
                                                    int M, int N, int K) {
    __shared__ unsigned short As[128][40];
    __shared__ unsigned short Bs[128][40];

    const int t = threadIdx.x;
    const int lane = t & 63;
    const int w = t >> 6;
    const int wr = w >> 1, wc = w & 1;
    const int row0 = blockIdx.y * 128;
    const int col0 = blockIdx.x * 128;

    const int srow = t >> 3;
    const int skc = (t & 7) << 2;

    const float* Abase = A + (size_t)row0 * K;
    const float* Bbase = Bm + (size_t)col0 * K;

    f32x4 acc[4][4];
#pragma unroll
    for (int m = 0; m < 4; ++m)
#pragma unroll
        for (int n = 0; n < 4; ++n)
#pragma unroll
            for (int j = 0; j < 4; ++j) acc[m][n][j] = 0.f;

    float4 pa[4], pb[4];
    const int q8 = (lane >> 4) << 3;
    const int frA = wr * 64 + (lane & 15);
    const int frB = wc * 64 + (lane & 15);
    const int NT = K >> 5;

#pragma unroll
    for (int i = 0; i < 4; ++i) {
        int r = i * 32 + srow;
        pa[i] = *reinterpret_cast<const float4*>(&Abase[(size_t)r * K + skc]);
        pb[i] = *reinterpret_cast<const float4*>(&Bbase[(size_t)r * K + skc]);
    }

    for (int kt = 0; kt < NT; ++kt) {
        __syncthreads();
#pragma unroll
        for (int i = 0; i < 4; ++i) {
            int r = i * 32 + srow;
            *reinterpret_cast<uint2*>(&As[r][skc]) = pack_bf16x4(pa[i]);
            *reinterpret_cast<uint2*>(&Bs[r][skc]) = pack_bf16x4(pb[i]);
        }
        __syncthreads();

        if (kt + 1 < NT) {
            const int k0n = (kt + 1) << 5;
#pragma unroll
            for (int i = 0; i < 4; ++i) {
                int r = i * 32 + srow;
                pa[i] = *reinterpret_cast<const float4*>(&Abase[(size_t)r * K + k0n + skc]);
                pb[i] = *reinterpret_cast<const float4*>(&Bbase[(size_t)r * K + k0n + skc]);
            }
        }

        short8 afr[4], bfr[4];
#pragma unroll
        for (int m = 0; m < 4; ++m)
            afr[m] = *reinterpret_cast<const short8*>(&As[frA + m * 16][q8]);
#pragma unroll
        for (int n = 0; n < 4; ++n)
            bfr[n] = *reinterpret_cast<const short8*>(&Bs[frB + n * 16][q8]);
#pragma unroll
        for (int m = 0; m < 4; ++m)
#pragma unroll
            for (int n = 0; n < 4; ++n)
                acc[m][n] = __builtin_amdgcn_mfma_f32_16x16x32_bf16(afr[m], bfr[n],
                                                                    acc[m][n], 0, 0, 0);
    }

    const int orow = row0 + wr * 64 + ((lane >> 4) << 2);
    const int ocol = col0 + wc * 64 + (lane & 15);
#pragma unroll
    for (int m = 0; m < 4; ++m)
#pragma unroll
        for (int n = 0; n < 4; ++n) {
            const int cg = ocol + n * 16;
#pragma unroll
            for (int j = 0; j < 4; ++j) {
                const int rg = orow + m * 16 + j;
                const float v = acc[m][n][j];
                if (MODE == 0) {
                    int q = cg >> 10, h = (cg >> 6) & 15, kk = cg & 63;
                    int b = rg >> 11, s = rg & 2047;
                    C[((((size_t)q * B_SZ + b) * NUM_HEADS + h) * S_LEN + s) * D_KD + kk] = v;
                } else {
                    C[(size_t)rg * N + cg] = v;
                }
            }
        }
}

// ---------------------------------------------------------------------------
// Flash attention v2 — swapped-operand 32x32 MFMA, in-register softmax.
// 512 threads = 8 warps; warp w owns q rows [q0+32w, q0+32w+31].
// Per KV-64 tile (staged in LDS, shared by all warps), two 32-t subtiles:
//   S^T = mfma(A=K, B=Q): lane holds S[q=l31][16 t's in regs, t=tloc(reg,hi)].
//   In-reg softmax (15 fmax + shfl_xor(32)); defer-max THR=8 (T13).
//   P packed bf16 + shfl_xor(32) half-exchange -> PV A-frags; PV=mfma(P,V^T).
// O accum: col=l31=d, row(reg)=q; alpha/inv redistribution via LDS broadcast.
// __launch_bounds__(512,2): VGPR cap 256 — guarantees no scratch spill.
// ---------------------------------------------------------------------------
__global__ __launch_bounds__(512, 2) void flash_attn_mfma_v2(const float* __restrict__ qkv,
                                                             float* __restrict__ attn_out) {
    const int qb = (int)gridDim.x - 1 - (int)blockIdx.x;   // heavy blocks first
    const int h = blockIdx.y;
    const int b = blockIdx.z;
    const int t = threadIdx.x;
    const int lane = t & 63;
    const int w = t >> 6;
    const int l31 = lane & 31;
    const int hi = lane >> 5;

    // Q phase: smem = Qs[256][72]; KV phase: Ks[64][72] | Vt[64][72] (aliased;
    // Q fragments are hoisted to registers before Ks overwrites).
    __shared__ unsigned short smem[256 * 72];
    __shared__ float fbuf[8][32];

    unsigned short* Qs = smem;
    unsigned short* Ks = smem;
    unsigned short* Vt = smem + 64 * 72;

    const size_t head_elems = (size_t)S_LEN * D_KD;
    const float* Qg = qkv + (((size_t)0 * B_SZ + b) * NUM_HEADS + h) * head_elems;
    const float* Kg = qkv + (((size_t)1 * B_SZ + b) * NUM_HEADS + h) * head_elems;
    const float* Vg = qkv + (((size_t)2 * B_SZ + b) * NUM_HEADS + h) * head_elems;

    const int q0 = qb * 256;
    const int qmin = q0 + 32 * w;   // warp's first q row

    // ---- stage Q tile [256][64] f32 -> bf16 LDS (scale 1/8 folded, exact)
#pragma unroll
    for (int lx = 0; lx < 8; ++lx) {
        int idx = t + lx * 512;
        int r = idx >> 4;
        int c = (idx & 15) << 2;
        float4 v = *reinterpret_cast<const float4*>(&Qg[(size_t)(q0 + r) * D_KD + c]);
        v.x *= 0.125f; v.y *= 0.125f; v.z *= 0.125f; v.w *= 0.125f;
        *reinterpret_cast<uint2*>(&Qs[r * 72 + c]) = pack_bf16x4(v);
    }
    __syncthreads();

    // Q B-fragments (hoisted): q = l31, k = 16*ks + 8*hi + 0..7
    short8 qfr[4];
#pragma unroll
    for (int ks = 0; ks < 4; ++ks)
        qfr[ks] = *reinterpret_cast<const short8*>(&Qs[(32 * w + l31) * 72 + 16 * ks + 8 * hi]);

    f32x16 oacc[2];
#pragma unroll
    for (int n = 0; n < 2; ++n)
#pragma unroll
        for (int j = 0; j < 16; ++j) oacc[n][j] = 0.f;
    float m = -1e30f, lsum = 0.f;

    const int nt = 4 * (qb + 1);
    for (int tt = 0; tt < nt; ++tt) {
        const int c0 = tt * 64;
        __syncthreads();   // prior reads of smem done (Q frags hoisted on iter 0)

        if (w < 4) {
            // warps 0..3: stage K [64][64] -> Ks bf16
#pragma unroll
            for (int lx = 0; lx < 4; ++lx) {
                int idx = t + lx * 256;
                int r = idx >> 4;
                int c = (idx & 15) << 2;
                float4 v = *reinterpret_cast<const float4*>(&Kg[(size_t)(c0 + r) * D_KD + c]);
                *reinterpret_cast<uint2*>(&Ks[r * 72 + c]) = pack_bf16x4(v);
            }
        } else {
            // warps 4..7: stage V transposed -> Vt[d][t] bf16 (4x4 reg transpose)
            int t2 = t - 256;
            int tb = (t2 >> 4) << 2;
            int dk0 = (t2 & 15) << 2;
            float4 vv[4];
#pragma unroll
            for (int i = 0; i < 4; ++i)
                vv[i] = *reinterpret_cast<const float4*>(&Vg[(size_t)(c0 + tb + i) * D_KD + dk0]);
            const float* vp = reinterpret_cast<const float*>(&vv[0]);
#pragma unroll
            for (int j = 0; j < 4; ++j) {
                uint2 u;
                u.x = f2bf(vp[0 * 4 + j]) | (f2bf(vp[1 * 4 + j]) << 16);
                u.y = f2bf(vp[2 * 4 + j]) | (f2bf(vp[3 * 4 + j]) << 16);
                *reinterpret_cast<uint2*>(&Vt[(dk0 + j) * 72 + tb]) = u;
            }
        }
        __syncthreads();

        for (int st = 0; st < 2; ++st) {
            const int t0s = c0 + 32 * st;
            if (t0s > qmin) break;          // wave-uniform; no barriers below
            const bool diag = (t0s == qmin);

            // ---- S^T = mfma(K, Q): lane holds S[q=l31][t=tloc(reg,hi)]
            f32x16 s;
#pragma unroll
            for (int j = 0; j < 16; ++j) s[j] = 0.f;
#pragma unroll
            for (int ks = 0; ks < 4; ++ks) {
                short8 ka = *reinterpret_cast<const short8*>(
                    &Ks[(32 * st + l31) * 72 + 16 * ks + 8 * hi]);
                s = __builtin_amdgcn_mfma_f32_32x32x16_bf16(ka, qfr[ks], s, 0, 0, 0);
            }
            if (diag) {
#pragma unroll
                for (int reg = 0; reg < 16; ++reg) {
                    const int tloc = (reg & 3) + 8 * (reg >> 2) + 4 * hi;
                    if (tloc > l31) s[reg] = -1e30f;
                }
            }

            // ---- in-register online softmax (q = l31; partner lane^32)
            float pm = s[0];
#pragma unroll
            for (int reg = 1; reg < 16; ++reg) pm = fmaxf(pm, s[reg]);
            pm = fmaxf(pm, __shfl_xor(pm, 32));

            if (!__all(pm <= m + 8.0f)) {     // defer-max (T13)
                const float mnew = fmaxf(m, pm);
                const float al = __expf(m - mnew);
                m = mnew;
                lsum *= al;
                fbuf[w][l31] = al;            // per-q alpha -> per-reg broadcast
#pragma unroll
                for (int g = 0; g < 4; ++g) {
                    float4 a4 = *reinterpret_cast<float4*>(&fbuf[w][8 * g + 4 * hi]);
                    const float* ap = reinterpret_cast<const float*>(&a4);
#pragma unroll
                    for (int j = 0; j < 4; ++j) {
                        oacc[0][4 * g + j] *= ap[j];
                        oacc[1][4 * g + j] *= ap[j];
                    }
                }
            }

            float p[16];
            float ps = 0.f;
#pragma unroll
            for (int reg = 0; reg < 16; ++reg) {
                p[reg] = __expf(s[reg] - m);
                ps += p[reg];
            }
            ps += __shfl_xor(ps, 32);
            lsum += ps;

            // ---- pack P to bf16, exchange halves, build PV A-frags
            unsigned pk[8], sw[8];
#pragma unroll
            for (int i = 0; i < 8; ++i) pk[i] = f2bf(p[2 * i]) | (f2bf(p[2 * i + 1]) << 16);
#pragma unroll
            for (int i = 0; i < 8; ++i) sw[i] = (unsigned)__shfl_xor((int)pk[i], 32);

            union { unsigned u[4]; short8 s8; } a0, a1;
            a0.u[0] = hi ? sw[2] : pk[0];
            a0.u[1] = hi ? sw[3] : pk[1];
            a0.u[2] = hi ? pk[2] : sw[0];
            a0.u[3] = hi ? pk[3] : sw[1];
            a1.u[0] = hi ? sw[6] : pk[4];
            a1.u[1] = hi ? sw[7] : pk[5];
            a1.u[2] = hi ? pk[6] : sw[4];
            a1.u[3] = hi ? pk[7] : sw[5];

            // ---- PV: O[q][d] += P[q][t] V[t][d]; B-frag from Vt[d][t]
#pragma unroll
            for (int n = 0; n < 2; ++n) {
                const unsigned short* vrow = &Vt[(32 * n + l31) * 72 + 32 * st + 8 * hi];
                short8 vb0 = *reinterpret_cast<const short8*>(vrow);
                short8 vb1 = *reinterpret_cast<const short8*>(vrow + 16);
                oacc[n] = __builtin_amdgcn_mfma_f32_32x32x16_bf16(a0.s8, vb0, oacc[n], 0, 0, 0);
                oacc[n] = __builtin_amdgcn_mfma_f32_32x32x16_bf16(a1.s8, vb1, oacc[n], 0, 0, 0);
            }
        }
    }

    // ---- epilogue: normalize (1/l via LDS broadcast) and store
    const float inv = 1.f / lsum;
    fbuf[w][l31] = inv;
#pragma unroll
    for (int g = 0; g < 4; ++g) {
        float4 i4 = *reinterpret_cast<float4*>(&fbuf[w][8 * g + 4 * hi]);
        const float* ip = reinterpret_cast<const float*>(&i4);
#pragma unroll
        for (int j = 0; j < 4; ++j) {
            const int reg = 4 * g + j;
            const int qrow = q0 + 32 * w + 8 * g + 4 * hi + j;
            const size_t base = ((size_t)(b * S_LEN + qrow)) * D_MODEL + h * D_KD + l31;
            attn_out[base] = oacc[0][reg] * ip[j];
            attn_out[base + 32] = oacc[1][reg] * ip[j];
        }
    }
}

// ---------------------------------------------------------------------------
extern "C" void kernel_launch(void* const* d_in, const int* in_sizes, int n_in,
                              void* d_out, int out_size, void* d_ws, size_t ws_size,
                              hipStream_t stream) {
    const float* x = (const float*)d_in[0];
    const float* w_qkv = (const float*)d_in[1];
    const float* w_o = (const float*)d_in[2];
    float* out = (float*)d_out;

    float* qkv = (float*)d_ws;
    float* attn = qkv + (size_t)3 * B_SZ * NUM_HEADS * S_LEN * D_KD;

    gemm_bt_mfma<0><<<dim3(QKV_N / 128, ROWS / 128), dim3(256), 0, stream>>>(
        x, w_qkv, qkv, ROWS, QKV_N, D_MODEL);
    flash_attn_mfma_v2<<<dim3(S_LEN / 256, NUM_HEADS, B_SZ), dim3(512), 0, stream>>>(qkv, attn);
    gemm_bt_mfma<1><<<dim3(D_MODEL / 128, ROWS / 128), dim3(256), 0, stream>>>(
        attn, w_o, out, ROWS, D_MODEL, D_MODEL);
}

// Round 7
// 311.668 us; speedup vs baseline: 1.7077x; 1.1690x over previous
//
#include <hip/hip_runtime.h>
#include <hip/hip_bf16.h>

// Causal MHA forward — full bf16 pipeline, fp32 softmax/accumulate.
//   x      [4, 2048, 1024]   d_in[0] fp32
//   w_qkv  [3, 16, 64, 1024] d_in[1] fp32 ([3072,1024], K contiguous)
//   w_o    [1024, 1024]      d_in[2] fp32 (y = attn_cat @ w_o^T)
//   out    [4, 2048, 1024]   d_out   fp32
// ws (bf16): xb 16.8MB | wqb 6.3MB | wob 2MB | qkv 50MB | attn_cat 16.8MB = 92MB.

#define D_MODEL 1024
#define NUM_HEADS 16
#define D_KD 64
#define B_SZ 4
#define S_LEN 2048
#define ROWS (B_SZ * S_LEN)   // 8192
#define QKV_N (3 * D_MODEL)   // 3072

typedef __attribute__((ext_vector_type(8))) short short8;
typedef __attribute__((ext_vector_type(4))) float f32x4;
typedef __attribute__((ext_vector_type(16))) float f32x16;
typedef unsigned short ushort_t;

__device__ __forceinline__ unsigned f2bf(float f) {
    unsigned u = __builtin_bit_cast(unsigned, f);
    return (u + 0x7FFFu + ((u >> 16) & 1u)) >> 16;   // RNE, finite inputs
}
__device__ __forceinline__ uint2 pack_bf16x4(float4 v) {
    uint2 u;
    u.x = f2bf(v.x) | (f2bf(v.y) << 16);
    u.y = f2bf(v.z) | (f2bf(v.w) << 16);
    return u;
}
// async global->LDS, 16B per lane. LDS dest = wave-uniform base + lane*16.
__device__ __forceinline__ void gload16(void* lds, const void* g) {
    __builtin_amdgcn_global_load_lds(
        (const __attribute__((address_space(1))) unsigned int*)(g),
        (__attribute__((address_space(3))) unsigned int*)(lds), 16, 0, 0);
}

// ---------------------------------------------------------------------------
// fp32 -> bf16 conversion (grid-stride, float4 in / uint2 out)
// ---------------------------------------------------------------------------
__global__ __launch_bounds__(256) void cvt_bf16(const float* __restrict__ src,
                                                ushort_t* __restrict__ dst, int n4) {
    int i = blockIdx.x * blockDim.x + threadIdx.x;
    const int stride = gridDim.x * blockDim.x;
    for (; i < n4; i += stride) {
        float4 v = reinterpret_cast<const float4*>(src)[i];
        *reinterpret_cast<uint2*>(&dst[(size_t)i * 4]) = pack_bf16x4(v);
    }
}

// ---------------------------------------------------------------------------
// MFMA GEMM (m97 structure): C = A * B^T. A:[M,K] bf16, B:[N,K] bf16.
// 128x128 tile, BK=32, 4 waves 2x2, 4x4 16x16x32 frags, global_load_lds x4.
// MODE 0: scatter bf16 into qkv[q][b][h][s][k], x0.125 on the Q third.
// MODE 1: fp32 row-major C.
// ---------------------------------------------------------------------------
template <int MODE>
__global__ __launch_bounds__(256) void gemm_bt_bf16(const ushort_t* __restrict__ A,
                                                    const ushort_t* __restrict__ Bm,
                                                    ushort_t* __restrict__ Cb,
                                                    float* __restrict__ Cf,
                                                    int M, int N, int K) {
    __shared__ ushort_t As[128 * 32];   // linear [row][32k], 64B rows
    __shared__ ushort_t Bs[128 * 32];

    const int t = threadIdx.x;
    const int lane = t & 63;
    const int w = t >> 6;
    const int wr = w >> 1, wc = w & 1;
    const int row0 = blockIdx.y * 128;
    const int col0 = blockIdx.x * 128;

    // staging: 16B slot j = i*256 + t -> LDS row j>>2, k8 = (j&3)*8
    const int srow = t >> 2;          // 0..63 (+64 for i=1)
    const int sk8 = (t & 3) << 3;     // 0,8,16,24

    const ushort_t* Ag = A + (size_t)(row0 + srow) * K + sk8;
    const ushort_t* Bg = Bm + (size_t)(col0 + srow) * K + sk8;
    ushort_t* ldsA0 = &As[(size_t)t * 8];
    ushort_t* ldsA1 = &As[(size_t)(t + 256) * 8];
    ushort_t* ldsB0 = &Bs[(size_t)t * 8];
    ushort_t* ldsB1 = &Bs[(size_t)(t + 256) * 8];

    f32x4 acc[4][4];
#pragma unroll
    for (int m = 0; m < 4; ++m)
#pragma unroll
        for (int n = 0; n < 4; ++n)
#pragma unroll
            for (int j = 0; j < 4; ++j) acc[m][n][j] = 0.f;

    const int q8 = (lane >> 4) << 3;
    const int frA = wr * 64 + (lane & 15);
    const int frB = wc * 64 + (lane & 15);
    const int NT = K >> 5;

    for (int kt = 0; kt < NT; ++kt) {
        const int k0 = kt << 5;
        __syncthreads();                       // prev frag reads done
        gload16(ldsA0, Ag + k0);
        gload16(ldsA1, Ag + (size_t)64 * K + k0);
        gload16(ldsB0, Bg + k0);
        gload16(ldsB1, Bg + (size_t)64 * K + k0);
        __syncthreads();                       // drains vmcnt(0)

        short8 afr[4], bfr[4];
#pragma unroll
        for (int m = 0; m < 4; ++m)
            afr[m] = *reinterpret_cast<const short8*>(&As[(frA + m * 16) * 32 + q8]);
#pragma unroll
        for (int n = 0; n < 4; ++n)
            bfr[n] = *reinterpret_cast<const short8*>(&Bs[(frB + n * 16) * 32 + q8]);
#pragma unroll
        for (int m = 0; m < 4; ++m)
#pragma unroll
            for (int n = 0; n < 4; ++n)
                acc[m][n] = __builtin_amdgcn_mfma_f32_16x16x32_bf16(afr[m], bfr[n],
                                                                    acc[m][n], 0, 0, 0);
    }

    // C/D frag: col = lane&15, row = (lane>>4)*4 + reg.
    const int orow = row0 + wr * 64 + ((lane >> 4) << 2);
    const int ocol = col0 + wc * 64 + (lane & 15);
#pragma unroll
    for (int m = 0; m < 4; ++m)
#pragma unroll
        for (int n = 0; n < 4; ++n) {
            const int cg = ocol + n * 16;
#pragma unroll
            for (int j = 0; j < 4; ++j) {
                const int rg = orow + m * 16 + j;
                float v = acc[m][n][j];
                if (MODE == 0) {
                    const int q = cg >> 10, hh = (cg >> 6) & 15, kk = cg & 63;
                    const int bb = rg >> 11, s = rg & 2047;
                    if (q == 0) v *= 0.125f;   // fold 1/sqrt(d_k) into Q
                    Cb[((((size_t)q * B_SZ + bb) * NUM_HEADS + hh) * S_LEN + s) * D_KD + kk] =
                        (ushort_t)f2bf(v);
                } else {
                    Cf[(size_t)rg * N + cg] = v;
                }
            }
        }
}

// ---------------------------------------------------------------------------
// Flash attention v3 — bf16 qkv in/out; swapped-operand 32x32 MFMA core
// (unchanged, verified round 6); staging is now pure copies (no f2bf).
// ---------------------------------------------------------------------------
__global__ __launch_bounds__(512, 2) void flash_attn_mfma_v3(const ushort_t* __restrict__ qkv,
                                                             ushort_t* __restrict__ attn_out) {
    const int qb = (int)gridDim.x - 1 - (int)blockIdx.x;   // heavy blocks first
    const int h = blockIdx.y;
    const int b = blockIdx.z;
    const int t = threadIdx.x;
    const int lane = t & 63;
    const int w = t >> 6;
    const int l31 = lane & 31;
    const int hi = lane >> 5;

    __shared__ ushort_t smem[256 * 72];
    __shared__ float fbuf[8][32];
    ushort_t* Qs = smem;
    ushort_t* Ks = smem;              // aliased; Q frags hoisted first
    ushort_t* Vt = smem + 64 * 72;

    const size_t head_elems = (size_t)S_LEN * D_KD;
    const ushort_t* Qg = qkv + (((size_t)0 * B_SZ + b) * NUM_HEADS + h) * head_elems;
    const ushort_t* Kg = qkv + (((size_t)1 * B_SZ + b) * NUM_HEADS + h) * head_elems;
    const ushort_t* Vg = qkv + (((size_t)2 * B_SZ + b) * NUM_HEADS + h) * head_elems;

    const int q0 = qb * 256;
    const int qmin = q0 + 32 * w;

    // ---- stage Q tile [256][64] bf16 (pre-scaled in GEMM epilogue)
#pragma unroll
    for (int lx = 0; lx < 4; ++lx) {
        int idx = t + lx * 512;
        int r = idx >> 3;
        int c8 = (idx & 7) << 3;
        *reinterpret_cast<uint4*>(&Qs[r * 72 + c8]) =
            *reinterpret_cast<const uint4*>(&Qg[(size_t)(q0 + r) * D_KD + c8]);
    }
    __syncthreads();

    short8 qfr[4];
#pragma unroll
    for (int ks = 0; ks < 4; ++ks)
        qfr[ks] = *reinterpret_cast<const short8*>(&Qs[(32 * w + l31) * 72 + 16 * ks + 8 * hi]);

    f32x16 oacc[2];
#pragma unroll
    for (int n = 0; n < 2; ++n)
#pragma unroll
        for (int j = 0; j < 16; ++j) oacc[n][j] = 0.f;
    float m = -1e30f, lsum = 0.f;

    const int nt = 4 * (qb + 1);
    for (int tt = 0; tt < nt; ++tt) {
        const int c0 = tt * 64;
        __syncthreads();

        if (w < 4) {
            // warps 0..3: copy K tile [64][64] bf16
#pragma unroll
            for (int i = 0; i < 2; ++i) {
                int j = t + i * 256;
                int r = j >> 3;
                int c8 = (j & 7) << 3;
                *reinterpret_cast<uint4*>(&Ks[r * 72 + c8]) =
                    *reinterpret_cast<const uint4*>(&Kg[(size_t)(c0 + r) * D_KD + c8]);
            }
        } else {
            // warps 4..7: V transposed -> Vt[d][t]; lanes vary tp -> conflict-free writes
            int t2 = t - 256;
            int tp = t2 & 31, dg = t2 >> 5;
            int t0 = tp * 2, d0 = dg * 8;
            uint4 va = *reinterpret_cast<const uint4*>(&Vg[(size_t)(c0 + t0) * D_KD + d0]);
            uint4 vb = *reinterpret_cast<const uint4*>(&Vg[(size_t)(c0 + t0 + 1) * D_KD + d0]);
            const ushort_t* ua = reinterpret_cast<const ushort_t*>(&va);
            const ushort_t* ub = reinterpret_cast<const ushort_t*>(&vb);
#pragma unroll
            for (int d = 0; d < 8; ++d) {
                unsigned u = (unsigned)ua[d] | ((unsigned)ub[d] << 16);
                *reinterpret_cast<unsigned*>(&Vt[(d0 + d) * 72 + t0]) = u;
            }
        }
        __syncthreads();

        for (int st = 0; st < 2; ++st) {
            const int t0s = c0 + 32 * st;
            if (t0s > qmin) break;          // wave-uniform; no barriers below
            const bool diag = (t0s == qmin);

            // ---- S^T = mfma(K, Q): lane holds S[q=l31][t=tloc(reg,hi)]
            f32x16 s;
#pragma unroll
            for (int j = 0; j < 16; ++j) s[j] = 0.f;
            __builtin_amdgcn_s_setprio(1);
#pragma unroll
            for (int ks = 0; ks < 4; ++ks) {
                short8 ka = *reinterpret_cast<const short8*>(
                    &Ks[(32 * st + l31) * 72 + 16 * ks + 8 * hi]);
                s = __builtin_amdgcn_mfma_f32_32x32x16_bf16(ka, qfr[ks], s, 0, 0, 0);
            }
            __builtin_amdgcn_s_setprio(0);
            if (diag) {
#pragma unroll
                for (int reg = 0; reg < 16; ++reg) {
                    const int tloc = (reg & 3) + 8 * (reg >> 2) + 4 * hi;
                    if (tloc > l31) s[reg] = -1e30f;
                }
            }

            // ---- in-register online softmax (q = l31; partner lane^32)
            float pm = s[0];
#pragma unroll
            for (int reg = 1; reg < 16; ++reg) pm = fmaxf(pm, s[reg]);
            pm = fmaxf(pm, __shfl_xor(pm, 32));

            if (!__all(pm <= m + 8.0f)) {     // defer-max (T13)
                const float mnew = fmaxf(m, pm);
                const float al = __expf(m - mnew);
                m = mnew;
                lsum *= al;
                fbuf[w][l31] = al;
#pragma unroll
                for (int g = 0; g < 4; ++g) {
                    float4 a4 = *reinterpret_cast<float4*>(&fbuf[w][8 * g + 4 * hi]);
                    const float* ap = reinterpret_cast<const float*>(&a4);
#pragma unroll
                    for (int j = 0; j < 4; ++j) {
                        oacc[0][4 * g + j] *= ap[j];
                        oacc[1][4 * g + j] *= ap[j];
                    }
                }
            }

            float p[16];
            float ps = 0.f;
#pragma unroll
            for (int reg = 0; reg < 16; ++reg) {
                p[reg] = __expf(s[reg] - m);
                ps += p[reg];
            }
            ps += __shfl_xor(ps, 32);
            lsum += ps;

            // ---- pack P bf16, exchange halves, build PV A-frags
            unsigned pk[8], sw[8];
#pragma unroll
            for (int i = 0; i < 8; ++i) pk[i] = f2bf(p[2 * i]) | (f2bf(p[2 * i + 1]) << 16);
#pragma unroll
            for (int i = 0; i < 8; ++i) sw[i] = (unsigned)__shfl_xor((int)pk[i], 32);

            union { unsigned u[4]; short8 s8; } a0, a1;
            a0.u[0] = hi ? sw[2] : pk[0];
            a0.u[1] = hi ? sw[3] : pk[1];
            a0.u[2] = hi ? pk[2] : sw[0];
            a0.u[3] = hi ? pk[3] : sw[1];
            a1.u[0] = hi ? sw[6] : pk[4];
            a1.u[1] = hi ? sw[7] : pk[5];
            a1.u[2] = hi ? pk[6] : sw[4];
            a1.u[3] = hi ? pk[7] : sw[5];

            // ---- PV: O[q][d] += P[q][t] V[t][d]
            __builtin_amdgcn_s_setprio(1);
#pragma unroll
            for (int n = 0; n < 2; ++n) {
                const ushort_t* vrow = &Vt[(32 * n + l31) * 72 + 32 * st + 8 * hi];
                short8 vb0 = *reinterpret_cast<const short8*>(vrow);
                short8 vb1 = *reinterpret_cast<const short8*>(vrow + 16);
                oacc[n] = __builtin_amdgcn_mfma_f32_32x32x16_bf16(a0.s8, vb0, oacc[n], 0, 0, 0);
                oacc[n] = __builtin_amdgcn_mfma_f32_32x32x16_bf16(a1.s8, vb1, oacc[n], 0, 0, 0);
            }
            __builtin_amdgcn_s_setprio(0);
        }
    }

    // ---- epilogue: normalize and store bf16 attn_cat [b, s, h*64 + d]
    const float inv = 1.f / lsum;
    fbuf[w][l31] = inv;
#pragma unroll
    for (int g = 0; g < 4; ++g) {
        float4 i4 = *reinterpret_cast<float4*>(&fbuf[w][8 * g + 4 * hi]);
        const float* ip = reinterpret_cast<const float*>(&i4);
#pragma unroll
        for (int j = 0; j < 4; ++j) {
            const int reg = 4 * g + j;
            const int qrow = q0 + 32 * w + 8 * g + 4 * hi + j;
            const size_t base = ((size_t)(b * S_LEN + qrow)) * D_MODEL + h * D_KD + l31;
            attn_out[base] = (ushort_t)f2bf(oacc[0][reg] * ip[j]);
            attn_out[base + 32] = (ushort_t)f2bf(oacc[1][reg] * ip[j]);
        }
    }
}

// ---------------------------------------------------------------------------
extern "C" void kernel_launch(void* const* d_in, const int* in_sizes, int n_in,
                              void* d_out, int out_size, void* d_ws, size_t ws_size,
                              hipStream_t stream) {
    const float* x = (const float*)d_in[0];
    const float* w_qkv = (const float*)d_in[1];
    const float* w_o = (const float*)d_in[2];
    float* out = (float*)d_out;

    ushort_t* xb = (ushort_t*)d_ws;                 //  8,388,608
    ushort_t* wqb = xb + 8388608;                   //  3,145,728
    ushort_t* wob = wqb + 3145728;                  //  1,048,576
    ushort_t* qkvb = wob + 1048576;                 // 25,165,824
    ushort_t* attnb = qkvb + 25165824;              //  8,388,608

    cvt_bf16<<<2048, 256, 0, stream>>>(x, xb, 8388608 / 4);
    cvt_bf16<<<1024, 256, 0, stream>>>(w_qkv, wqb, 3145728 / 4);
    cvt_bf16<<<512, 256, 0, stream>>>(w_o, wob, 1048576 / 4);

    gemm_bt_bf16<0><<<dim3(QKV_N / 128, ROWS / 128), dim3(256), 0, stream>>>(
        xb, wqb, qkvb, nullptr, ROWS, QKV_N, D_MODEL);
    flash_attn_mfma_v3<<<dim3(S_LEN / 256, NUM_HEADS, B_SZ), dim3(512), 0, stream>>>(qkvb, attnb);
    gemm_bt_bf16<1><<<dim3(D_MODEL / 128, ROWS / 128), dim3(256), 0, stream>>>(
        attnb, wob, nullptr, out, ROWS, D_MODEL, D_MODEL);
}

// Round 8
// 310.208 us; speedup vs baseline: 1.7158x; 1.0047x over previous
//
#include <hip/hip_runtime.h>
#include <hip/hip_bf16.h>

// Causal MHA forward — full bf16 pipeline, fp32 softmax/accumulate.
//   x      [4, 2048, 1024]   d_in[0] fp32
//   w_qkv  [3, 16, 64, 1024] d_in[1] fp32 ([3072,1024], K contiguous)
//   w_o    [1024, 1024]      d_in[2] fp32 (y = attn_cat @ w_o^T)
//   out    [4, 2048, 1024]   d_out   fp32
// ws (bf16): xb | wqb | wob | qkv | attn_cat = 92 MB.
// Softmax computed in exp2-domain: Q pre-scaled by 0.125*log2(e) in the QKV
// GEMM epilogue, so flash uses native v_exp_f32 (exp2) directly.

#define D_MODEL 1024
#define NUM_HEADS 16
#define D_KD 64
#define B_SZ 4
#define S_LEN 2048
#define ROWS (B_SZ * S_LEN)   // 8192
#define QKV_N (3 * D_MODEL)   // 3072

#define QSCALE 0.18033688f    // 0.125 * log2(e)
#define DEFER_THR 11.5415603f // 8 * log2(e)

typedef __attribute__((ext_vector_type(8))) short short8;
typedef __attribute__((ext_vector_type(4))) float f32x4;
typedef __attribute__((ext_vector_type(16))) float f32x16;
typedef unsigned short ushort_t;

// bf16 via compiler casts -> v_cvt_pk_bf16_f32 (m240: faster than manual RNE)
__device__ __forceinline__ ushort_t bf1(float a) {
    return __builtin_bit_cast(unsigned short, __float2bfloat16(a));
}
__device__ __forceinline__ unsigned packbf2(float a, float b) {
    return (unsigned)bf1(a) | ((unsigned)bf1(b) << 16);
}
// async global->LDS, 16B per lane. LDS dest = wave-uniform base + lane*16.
__device__ __forceinline__ void gload16(void* lds, const void* g) {
    __builtin_amdgcn_global_load_lds(
        (const __attribute__((address_space(1))) unsigned int*)(g),
        (__attribute__((address_space(3))) unsigned int*)(lds), 16, 0, 0);
}

// ---------------------------------------------------------------------------
// fp32 -> bf16 conversion (grid-stride, float4 in / uint2 out)
// ---------------------------------------------------------------------------
__global__ __launch_bounds__(256) void cvt_bf16(const float* __restrict__ src,
                                                ushort_t* __restrict__ dst, int n4) {
    int i = blockIdx.x * blockDim.x + threadIdx.x;
    const int stride = gridDim.x * blockDim.x;
    for (; i < n4; i += stride) {
        float4 v = reinterpret_cast<const float4*>(src)[i];
        uint2 u;
        u.x = packbf2(v.x, v.y);
        u.y = packbf2(v.z, v.w);
        *reinterpret_cast<uint2*>(&dst[(size_t)i * 4]) = u;
    }
}

// ---------------------------------------------------------------------------
// MFMA GEMM (m97 structure): C = A * B^T. A:[M,K] bf16, B:[N,K] bf16.
// 128x128 tile, BK=32, 4 waves 2x2, 4x4 16x16x32 frags, global_load_lds x4.
// MODE 0: scatter bf16 into qkv[q][b][h][s][k], xQSCALE on the Q third.
// MODE 1: fp32 row-major C.
// ---------------------------------------------------------------------------
template <int MODE>
__global__ __launch_bounds__(256) void gemm_bt_bf16(const ushort_t* __restrict__ A,
                                                    const ushort_t* __restrict__ Bm,
                                                    ushort_t* __restrict__ Cb,
                                                    float* __restrict__ Cf,
                                                    int M, int N, int K) {
    __shared__ ushort_t As[128 * 32];   // linear [row][32k], 64B rows
    __shared__ ushort_t Bs[128 * 32];

    const int t = threadIdx.x;
    const int lane = t & 63;
    const int w = t >> 6;
    const int wr = w >> 1, wc = w & 1;
    const int row0 = blockIdx.y * 128;
    const int col0 = blockIdx.x * 128;

    const int srow = t >> 2;          // 0..63 (+64 for second half)
    const int sk8 = (t & 3) << 3;     // 0,8,16,24

    const ushort_t* Ag = A + (size_t)(row0 + srow) * K + sk8;
    const ushort_t* Bg = Bm + (size_t)(col0 + srow) * K + sk8;
    ushort_t* ldsA0 = &As[(size_t)t * 8];
    ushort_t* ldsA1 = &As[(size_t)(t + 256) * 8];
    ushort_t* ldsB0 = &Bs[(size_t)t * 8];
    ushort_t* ldsB1 = &Bs[(size_t)(t + 256) * 8];

    f32x4 acc[4][4];
#pragma unroll
    for (int m = 0; m < 4; ++m)
#pragma unroll
        for (int n = 0; n < 4; ++n)
#pragma unroll
            for (int j = 0; j < 4; ++j) acc[m][n][j] = 0.f;

    const int q8 = (lane >> 4) << 3;
    const int frA = wr * 64 + (lane & 15);
    const int frB = wc * 64 + (lane & 15);
    const int NT = K >> 5;

    for (int kt = 0; kt < NT; ++kt) {
        const int k0 = kt << 5;
        __syncthreads();                       // prev frag reads done
        gload16(ldsA0, Ag + k0);
        gload16(ldsA1, Ag + (size_t)64 * K + k0);
        gload16(ldsB0, Bg + k0);
        gload16(ldsB1, Bg + (size_t)64 * K + k0);
        __syncthreads();                       // drains vmcnt(0)

        short8 afr[4], bfr[4];
#pragma unroll
        for (int m = 0; m < 4; ++m)
            afr[m] = *reinterpret_cast<const short8*>(&As[(frA + m * 16) * 32 + q8]);
#pragma unroll
        for (int n = 0; n < 4; ++n)
            bfr[n] = *reinterpret_cast<const short8*>(&Bs[(frB + n * 16) * 32 + q8]);
#pragma unroll
        for (int m = 0; m < 4; ++m)
#pragma unroll
            for (int n = 0; n < 4; ++n)
                acc[m][n] = __builtin_amdgcn_mfma_f32_16x16x32_bf16(afr[m], bfr[n],
                                                                    acc[m][n], 0, 0, 0);
    }

    // C/D frag: col = lane&15, row = (lane>>4)*4 + reg.
    const int orow = row0 + wr * 64 + ((lane >> 4) << 2);
    const int ocol = col0 + wc * 64 + (lane & 15);
#pragma unroll
    for (int m = 0; m < 4; ++m)
#pragma unroll
        for (int n = 0; n < 4; ++n) {
            const int cg = ocol + n * 16;
#pragma unroll
            for (int j = 0; j < 4; ++j) {
                const int rg = orow + m * 16 + j;
                float v = acc[m][n][j];
                if (MODE == 0) {
                    const int q = cg >> 10, hh = (cg >> 6) & 15, kk = cg & 63;
                    const int bb = rg >> 11, s = rg & 2047;
                    if (q == 0) v *= QSCALE;   // fold 1/sqrt(d_k)*log2e into Q
                    Cb[((((size_t)q * B_SZ + bb) * NUM_HEADS + hh) * S_LEN + s) * D_KD + kk] =
                        bf1(v);
                } else {
                    Cf[(size_t)rg * N + cg] = v;
                }
            }
        }
}

// ---------------------------------------------------------------------------
// Flash attention v4 — bf16 qkv in/out; swapped-operand 32x32 MFMA core
// (verified rounds 6-7). T14 async-STAGE: next tile's K/V global loads are
// issued into registers right after the compute barrier; ds_write happens at
// the top of the next iteration. exp2-domain softmax (Q pre-scaled).
// ---------------------------------------------------------------------------
__global__ __launch_bounds__(512, 2) void flash_attn_mfma_v4(const ushort_t* __restrict__ qkv,
                                                             ushort_t* __restrict__ attn_out) {
    const int qb = (int)gridDim.x - 1 - (int)blockIdx.x;   // heavy blocks first
    const int h = blockIdx.y;
    const int b = blockIdx.z;
    const int t = threadIdx.x;
    const int lane = t & 63;
    const int w = t >> 6;
    const int l31 = lane & 31;
    const int hi = lane >> 5;

    __shared__ ushort_t smem[256 * 72];
    __shared__ float fbuf[8][32];
    ushort_t* Qs = smem;
    ushort_t* Ks = smem;              // aliased; Q frags hoisted first
    ushort_t* Vt = smem + 64 * 72;

    const size_t head_elems = (size_t)S_LEN * D_KD;
    const ushort_t* Qg = qkv + (((size_t)0 * B_SZ + b) * NUM_HEADS + h) * head_elems;
    const ushort_t* Kg = qkv + (((size_t)1 * B_SZ + b) * NUM_HEADS + h) * head_elems;
    const ushort_t* Vg = qkv + (((size_t)2 * B_SZ + b) * NUM_HEADS + h) * head_elems;

    const int q0 = qb * 256;
    const int qmin = q0 + 32 * w;
    const int nt = 4 * (qb + 1);

    // staging addresses (fixed per thread)
    const int krow0 = t >> 3, kc8 = (t & 7) << 3;          // K warps: rows t>>3, t>>3+32
    const int tp = (t & 31) * 2, dg8 = ((t & 255) >> 5) << 3;  // V warps (t>=256)

    // ---- prologue: issue KV tile 0 loads into regs (fly under Q staging)
    uint4 kreg0, kreg1, vreg0, vreg1;
    if (w < 4) {
        kreg0 = *reinterpret_cast<const uint4*>(&Kg[(size_t)krow0 * D_KD + kc8]);
        kreg1 = *reinterpret_cast<const uint4*>(&Kg[(size_t)(krow0 + 32) * D_KD + kc8]);
    } else {
        vreg0 = *reinterpret_cast<const uint4*>(&Vg[(size_t)tp * D_KD + dg8]);
        vreg1 = *reinterpret_cast<const uint4*>(&Vg[(size_t)(tp + 1) * D_KD + dg8]);
    }

    // ---- stage Q tile [256][64] bf16 (pre-scaled by QSCALE in GEMM)
#pragma unroll
    for (int lx = 0; lx < 4; ++lx) {
        int idx = t + lx * 512;
        int r = idx >> 3;
        int c8 = (idx & 7) << 3;
        *reinterpret_cast<uint4*>(&Qs[r * 72 + c8]) =
            *reinterpret_cast<const uint4*>(&Qg[(size_t)(q0 + r) * D_KD + c8]);
    }
    __syncthreads();

    short8 qfr[4];
#pragma unroll
    for (int ks = 0; ks < 4; ++ks)
        qfr[ks] = *reinterpret_cast<const short8*>(&Qs[(32 * w + l31) * 72 + 16 * ks + 8 * hi]);

    f32x16 oacc[2];
#pragma unroll
    for (int n = 0; n < 2; ++n)
#pragma unroll
        for (int j = 0; j < 16; ++j) oacc[n][j] = 0.f;
    float m = -1e30f, lsum = 0.f;

    for (int tt = 0; tt < nt; ++tt) {
        __syncthreads();   // smem consumers done (Q frags hoisted on iter 0)

        // ---- ds_write staged regs (tile tt)
        if (w < 4) {
            *reinterpret_cast<uint4*>(&Ks[krow0 * 72 + kc8]) = kreg0;
            *reinterpret_cast<uint4*>(&Ks[(krow0 + 32) * 72 + kc8]) = kreg1;
        } else {
            const ushort_t* ua = reinterpret_cast<const ushort_t*>(&vreg0);
            const ushort_t* ub = reinterpret_cast<const ushort_t*>(&vreg1);
#pragma unroll
            for (int d = 0; d < 8; ++d) {
                unsigned u = (unsigned)ua[d] | ((unsigned)ub[d] << 16);
                *reinterpret_cast<unsigned*>(&Vt[(dg8 + d) * 72 + tp]) = u;
            }
        }
        __syncthreads();

        // ---- T14: issue next tile's loads (fly under compute below)
        if (tt + 1 < nt) {
            const int cn = (tt + 1) * 64;
            if (w < 4) {
                kreg0 = *reinterpret_cast<const uint4*>(&Kg[(size_t)(cn + krow0) * D_KD + kc8]);
                kreg1 = *reinterpret_cast<const uint4*>(&Kg[(size_t)(cn + krow0 + 32) * D_KD + kc8]);
            } else {
                vreg0 = *reinterpret_cast<const uint4*>(&Vg[(size_t)(cn + tp) * D_KD + dg8]);
                vreg1 = *reinterpret_cast<const uint4*>(&Vg[(size_t)(cn + tp + 1) * D_KD + dg8]);
            }
        }

        const int c0 = tt * 64;
        for (int st = 0; st < 2; ++st) {
            const int t0s = c0 + 32 * st;
            if (t0s > qmin) break;          // wave-uniform; no barriers below
            const bool diag = (t0s == qmin);

            // ---- S^T = mfma(K, Q): lane holds S[q=l31][t=tloc(reg,hi)]
            f32x16 s;
#pragma unroll
            for (int j = 0; j < 16; ++j) s[j] = 0.f;
            __builtin_amdgcn_s_setprio(1);
#pragma unroll
            for (int ks = 0; ks < 4; ++ks) {
                short8 ka = *reinterpret_cast<const short8*>(
                    &Ks[(32 * st + l31) * 72 + 16 * ks + 8 * hi]);
                s = __builtin_amdgcn_mfma_f32_32x32x16_bf16(ka, qfr[ks], s, 0, 0, 0);
            }
            __builtin_amdgcn_s_setprio(0);
            if (diag) {
#pragma unroll
                for (int reg = 0; reg < 16; ++reg) {
                    const int tloc = (reg & 3) + 8 * (reg >> 2) + 4 * hi;
                    if (tloc > l31) s[reg] = -1e30f;
                }
            }

            // ---- in-register online softmax, exp2 domain (q = l31)
            float pm = s[0];
#pragma unroll
            for (int reg = 1; reg < 16; ++reg) pm = fmaxf(pm, s[reg]);
            pm = fmaxf(pm, __shfl_xor(pm, 32));

            if (!__all(pm <= m + DEFER_THR)) {   // defer-max (T13)
                const float mnew = fmaxf(m, pm);
                const float al = exp2f(m - mnew);
                m = mnew;
                lsum *= al;
                fbuf[w][l31] = al;
#pragma unroll
                for (int g = 0; g < 4; ++g) {
                    float4 a4 = *reinterpret_cast<float4*>(&fbuf[w][8 * g + 4 * hi]);
                    const float* ap = reinterpret_cast<const float*>(&a4);
#pragma unroll
                    for (int j = 0; j < 4; ++j) {
                        oacc[0][4 * g + j] *= ap[j];
                        oacc[1][4 * g + j] *= ap[j];
                    }
                }
            }

            float p[16];
            float ps = 0.f;
#pragma unroll
            for (int reg = 0; reg < 16; ++reg) {
                p[reg] = exp2f(s[reg] - m);
                ps += p[reg];
            }
            ps += __shfl_xor(ps, 32);
            lsum += ps;

            // ---- pack P bf16 (compiler cvt_pk), exchange halves, A-frags
            unsigned pk[8], sw[8];
#pragma unroll
            for (int i = 0; i < 8; ++i) pk[i] = packbf2(p[2 * i], p[2 * i + 1]);
#pragma unroll
            for (int i = 0; i < 8; ++i) sw[i] = (unsigned)__shfl_xor((int)pk[i], 32);

            union { unsigned u[4]; short8 s8; } a0, a1;
            a0.u[0] = hi ? sw[2] : pk[0];
            a0.u[1] = hi ? sw[3] : pk[1];
            a0.u[2] = hi ? pk[2] : sw[0];
            a0.u[3] = hi ? pk[3] : sw[1];
            a1.u[0] = hi ? sw[6] : pk[4];
            a1.u[1] = hi ? sw[7] : pk[5];
            a1.u[2] = hi ? pk[6] : sw[4];
            a1.u[3] = hi ? pk[7] : sw[5];

            // ---- PV: O[q][d] += P[q][t] V[t][d]
            __builtin_amdgcn_s_setprio(1);
#pragma unroll
            for (int n = 0; n < 2; ++n) {
                const ushort_t* vrow = &Vt[(32 * n + l31) * 72 + 32 * st + 8 * hi];
                short8 vb0 = *reinterpret_cast<const short8*>(vrow);
                short8 vb1 = *reinterpret_cast<const short8*>(vrow + 16);
                oacc[n] = __builtin_amdgcn_mfma_f32_32x32x16_bf16(a0.s8, vb0, oacc[n], 0, 0, 0);
                oacc[n] = __builtin_amdgcn_mfma_f32_32x32x16_bf16(a1.s8, vb1, oacc[n], 0, 0, 0);
            }
            __builtin_amdgcn_s_setprio(0);
        }
    }

    // ---- epilogue: normalize and store bf16 attn_cat [b, s, h*64 + d]
    const float inv = 1.f / lsum;
    fbuf[w][l31] = inv;
#pragma unroll
    for (int g = 0; g < 4; ++g) {
        float4 i4 = *reinterpret_cast<float4*>(&fbuf[w][8 * g + 4 * hi]);
        const float* ip = reinterpret_cast<const float*>(&i4);
#pragma unroll
        for (int j = 0; j < 4; ++j) {
            const int reg = 4 * g + j;
            const int qrow = q0 + 32 * w + 8 * g + 4 * hi + j;
            const size_t base = ((size_t)(b * S_LEN + qrow)) * D_MODEL + h * D_KD + l31;
            attn_out[base] = bf1(oacc[0][reg] * ip[j]);
            attn_out[base + 32] = bf1(oacc[1][reg] * ip[j]);
        }
    }
}

// ---------------------------------------------------------------------------
extern "C" void kernel_launch(void* const* d_in, const int* in_sizes, int n_in,
                              void* d_out, int out_size, void* d_ws, size_t ws_size,
                              hipStream_t stream) {
    const float* x = (const float*)d_in[0];
    const float* w_qkv = (const float*)d_in[1];
    const float* w_o = (const float*)d_in[2];
    float* out = (float*)d_out;

    ushort_t* xb = (ushort_t*)d_ws;                 //  8,388,608
    ushort_t* wqb = xb + 8388608;                   //  3,145,728
    ushort_t* wob = wqb + 3145728;                  //  1,048,576
    ushort_t* qkvb = wob + 1048576;                 // 25,165,824
    ushort_t* attnb = qkvb + 25165824;              //  8,388,608

    cvt_bf16<<<2048, 256, 0, stream>>>(x, xb, 8388608 / 4);
    cvt_bf16<<<1024, 256, 0, stream>>>(w_qkv, wqb, 3145728 / 4);
    cvt_bf16<<<512, 256, 0, stream>>>(w_o, wob, 1048576 / 4);

    gemm_bt_bf16<0><<<dim3(QKV_N / 128, ROWS / 128), dim3(256), 0, stream>>>(
        xb, wqb, qkvb, nullptr, ROWS, QKV_N, D_MODEL);
    flash_attn_mfma_v4<<<dim3(S_LEN / 256, NUM_HEADS, B_SZ), dim3(512), 0, stream>>>(qkvb, attnb);
    gemm_bt_bf16<1><<<dim3(D_MODEL / 128, ROWS / 128), dim3(256), 0, stream>>>(
        attnb, wob, nullptr, out, ROWS, D_MODEL, D_MODEL);
}